// Round 9
// baseline (427.751 us; speedup 1.0000x reference)
//
#include <hip/hip_runtime.h>
#include <hip/hip_bf16.h>

typedef float f32x4 __attribute__((ext_vector_type(4)));
typedef __bf16 bf16x8 __attribute__((ext_vector_type(8)));
typedef unsigned short ushort_t;
typedef ushort_t u16x8 __attribute__((ext_vector_type(8)));

// ---------------------------------------------------------------------------
// fp32 -> bf16 round-to-nearest-even
// ---------------------------------------------------------------------------
__device__ inline ushort_t f2bf_rne(float f) {
  unsigned u = __builtin_bit_cast(unsigned, f);
  unsigned r = (u + 0x7fffu + ((u >> 16) & 1u)) >> 16;
  return (ushort_t)r;
}

// ---------------------------------------------------------------------------
// Kernel 1: 2:4 prune (exact fp32 argsort-stable semantics) + cast to bf16.
// ---------------------------------------------------------------------------
__global__ void prune_cast_kernel(const float* __restrict__ x,
                                  ushort_t* __restrict__ xsp, long n8) {
  long i = (long)blockIdx.x * blockDim.x + threadIdx.x;
  if (i >= n8) return;
  const float4* p = reinterpret_cast<const float4*>(x);
  float4 g0 = p[2 * i];
  float4 g1 = p[2 * i + 1];
  float v[8] = {g0.x, g0.y, g0.z, g0.w, g1.x, g1.y, g1.z, g1.w};
  u16x8 o;
#pragma unroll
  for (int g = 0; g < 2; ++g) {
    float a[4];
#pragma unroll
    for (int j = 0; j < 4; ++j) a[j] = fabsf(v[g * 4 + j]);
#pragma unroll
    for (int j = 0; j < 4; ++j) {
      int rank = 0;
#pragma unroll
      for (int k = 0; k < 4; ++k) {
        if (k == j) continue;
        rank += (a[k] < a[j]) || (a[k] == a[j] && k < j);
      }
      o[g * 4 + j] = (rank >= 2) ? f2bf_rne(v[g * 4 + j]) : (ushort_t)0;
    }
  }
  reinterpret_cast<u16x8*>(xsp)[i] = o;
}

// ---------------------------------------------------------------------------
// Kernel 2: fp32 -> bf16 cast of the weight matrix.
// ---------------------------------------------------------------------------
__global__ void cast_bf16_kernel(const float* __restrict__ w,
                                 ushort_t* __restrict__ wb, long n8) {
  long i = (long)blockIdx.x * blockDim.x + threadIdx.x;
  if (i >= n8) return;
  const float4* p = reinterpret_cast<const float4*>(w);
  float4 g0 = p[2 * i];
  float4 g1 = p[2 * i + 1];
  u16x8 o;
  o[0] = f2bf_rne(g0.x); o[1] = f2bf_rne(g0.y);
  o[2] = f2bf_rne(g0.z); o[3] = f2bf_rne(g0.w);
  o[4] = f2bf_rne(g1.x); o[5] = f2bf_rne(g1.y);
  o[6] = f2bf_rne(g1.z); o[7] = f2bf_rne(g1.w);
  reinterpret_cast<u16x8*>(wb)[i] = o;
}

// ---------------------------------------------------------------------------
// Kernel 3: 256x256 bf16 GEMM, B direct-to-register, ONE barrier per K-tile.
// C[m][n] = sum_k A[m][k]*B[n][k].  8 waves (2Mx4N), BK=64.
//
// A path: staged to LDS (64 KiB, double-buffered, 3-bit XOR swizzle:
//   physical chunk = logical ^ (row&7) -> 0 bank conflicts).
// B path: per-lane global->register loads (no LDS).  Lane l of frag (ni,s)
//   reads B[b_row0+wc*64+ni*16+(l&15)][kt+s*32+(l>>4)*8] -- the exact same
//   elements the old LDS path delivered.  The 4 k-groups of a row coalesce
//   into one 64B L2 line; B panel is L3-resident.
// LDS traffic/tile drops 192->128 KB -> off the critical path (MFMA 2480 cyc
// vs LDS 1500).  B loads are compiler-visible: counted vmcnt waits are
// automatic; issue order = consumption order.
// Single barrier/tile: A(t+1) stages to OPPOSITE parity (whose reads were
// consumed before tile t-1's end barrier); B has no LDS hazard.  Tile-end
// vmcnt(0) only waits the 4 A-stage loads issued a full tile earlier.
// ---------------------------------------------------------------------------
#define BARM()                              \
  asm volatile("" ::: "memory");            \
  __builtin_amdgcn_s_barrier();             \
  asm volatile("" ::: "memory");
#define WAIT_VM0() asm volatile("s_waitcnt vmcnt(0)" ::: "memory")

#define STAGE_A(t1, h, par)                                                    \
  {                                                                            \
    const ushort_t* g0 =                                                       \
        A + (a_row0 + (h) * 128 + srow) * (long)Kd + (t1) * 64 + scol;         \
    const ushort_t* g1 =                                                       \
        A + (a_row0 + (h) * 128 + srow + 8) * (long)Kd + (t1) * 64 + scol;     \
    ushort_t* l0 = &ldsA[((par) * 2 + (h)) * 8192 + w * 1024];                 \
    __builtin_amdgcn_global_load_lds(                                          \
        (const __attribute__((address_space(1))) void*)g0,                     \
        (__attribute__((address_space(3))) void*)l0, 16, 0, 0);                \
    __builtin_amdgcn_global_load_lds(                                          \
        (const __attribute__((address_space(1))) void*)g1,                     \
        (__attribute__((address_space(3))) void*)(l0 + 512), 16, 0, 0);        \
  }

#define LDA_FRAG(dst, par, mi, s)                                              \
  dst = *reinterpret_cast<const bf16x8*>(                                      \
      reinterpret_cast<const char*>(ldsA) + ((par) * 2 + wr) * 16384 +         \
      (mi) * 2048 + ((s) ? roff1 : roff0));

// B global->register fragment load (compiler-visible, auto vmcnt waits)
#define LDB_G(dst, ni, s, t)                                                   \
  dst = *reinterpret_cast<const bf16x8*>(bpB + (long)(ni) * 16 * Kd +          \
                                         (t) * 64 + (s) * 32);

// s-outer: distance 8 between dependent updates of the same acc register.
#define MFMA_Q(MH, NH)                                                         \
  __builtin_amdgcn_s_setprio(1);                                               \
  _Pragma("unroll") for (int s = 0; s < 2; ++s)                                \
  _Pragma("unroll") for (int mi = 0; mi < 4; ++mi)                             \
  _Pragma("unroll") for (int ni = 0; ni < 2; ++ni)                             \
      acc[(MH) * 4 + mi][(NH) * 2 + ni] =                                      \
          __builtin_amdgcn_mfma_f32_16x16x32_bf16(                             \
              af[mi][s], bfr[(NH) * 2 + ni][s],                                \
              acc[(MH) * 4 + mi][(NH) * 2 + ni], 0, 0, 0);                     \
  __builtin_amdgcn_s_setprio(0);

#define KTILE(t, PAR)                                                          \
  {                                                                            \
    const int tA = ((t) + 1 < NT) ? (t) + 1 : NT - 1;                          \
    /* B regs for THIS tile, consumption order (b0,b1 feed Q(0,0) first) */    \
    LDB_G(bfr[0][0], 0, 0, t) LDB_G(bfr[0][1], 0, 1, t)                        \
    LDB_G(bfr[1][0], 1, 0, t) LDB_G(bfr[1][1], 1, 1, t)                        \
    LDB_G(bfr[2][0], 2, 0, t) LDB_G(bfr[2][1], 2, 1, t)                        \
    LDB_G(bfr[3][0], 3, 0, t) LDB_G(bfr[3][1], 3, 1, t)                        \
    /* stage A(t+1) into opposite parity -- full-tile flight */                \
    STAGE_A(tA, 0, (PAR) ^ 1)                                                  \
    STAGE_A(tA, 1, (PAR) ^ 1)                                                  \
    /* A mh0 reads + first two quadrants */                                    \
    _Pragma("unroll") for (int mi = 0; mi < 4; ++mi)                           \
    _Pragma("unroll") for (int s = 0; s < 2; ++s)                              \
        LDA_FRAG(af[mi][s], PAR, mi, s)                                        \
    MFMA_Q(0, 0)                                                               \
    MFMA_Q(0, 1)                                                               \
    /* A mh1 reads + last two quadrants */                                     \
    _Pragma("unroll") for (int mi = 0; mi < 4; ++mi)                           \
    _Pragma("unroll") for (int s = 0; s < 2; ++s)                              \
        LDA_FRAG(af[mi][s], PAR, 4 + mi, s)                                    \
    MFMA_Q(1, 1)                                                               \
    MFMA_Q(1, 0)                                                               \
    WAIT_VM0();                                                                \
    BARM()                                                                     \
  }

__global__ __launch_bounds__(512, 1) void gemm256_kernel(
    const ushort_t* __restrict__ A,  // [M][K] bf16 (pruned x)
    const ushort_t* __restrict__ B,  // [N][K] bf16 (weight)
    float* __restrict__ C,           // [M][N] fp32
    int M, int N, int Kd) {
  __shared__ ushort_t ldsA[4 * 8192];  // 4 slots x 16 KiB (par,half) = 64 KiB

  const int tid = threadIdx.x;
  const int lane = tid & 63;
  const int w = tid >> 6;   // wave 0..7
  const int wr = w >> 2;    // 0..1 -> 128-row half
  const int wc = w & 3;     // 0..3 -> 64-col slab

  // XCD-bijective grid swizzle (gridDim.x % 8 == 0)
  const int b = blockIdx.x;
  const int wg = (b & 7) * (gridDim.x >> 3) + (b >> 3);
  const int nbn = N / 256;
  const int bm = wg / nbn, bn = wg % nbn;
  const long a_row0 = (long)bm * 256;
  const long b_row0 = (long)bn * 256;
  const int NT = Kd / 64;

  // A staging: instr i of wave w, lane l writes LINEAR physical (row
  // 16w+8i+(l>>3), chunk l&7); swizzle physical(r,c) <- logical(r, c^(r&7))
  // -> global SOURCE chunk = (l&7) ^ ((l>>3)&7)  (same for both instrs).
  const int srow = w * 16 + (lane >> 3);
  const int scol = (((lane & 7) ^ ((lane >> 3) & 7)) << 3);  // ushort units

  // A fragment read: logical (row rl, chunk q|s<<2) -> physical chunk
  // (q|s<<2) ^ (rl&7); s folded inside the XOR -> two precomputed offsets.
  const int rl = lane & 15;
  const int q = lane >> 4;
  const int roff0 = rl * 128 + (((q) ^ (rl & 7)) << 4);
  const int roff1 = rl * 128 + (((q | 4) ^ (rl & 7)) << 4);

  // B per-lane global base: row = b_row0 + wc*64 + rl, k-offset q*8
  const ushort_t* bpB = B + (long)(b_row0 + wc * 64 + rl) * Kd + q * 8;

  f32x4 acc[8][4];
#pragma unroll
  for (int i = 0; i < 8; ++i)
#pragma unroll
    for (int j = 0; j < 4; ++j) acc[i][j] = f32x4{0.f, 0.f, 0.f, 0.f};

  bf16x8 af[4][2];   // A fragments (mh0 then mh1; compiler renames)
  bf16x8 bfr[4][2];  // B fragments for the current tile (registers)

  // ---- prologue: stage A tile 0 into parity 0, drain, sync ----
  STAGE_A(0, 0, 0)
  STAGE_A(0, 1, 0)
  WAIT_VM0();
  BARM()

  for (int t = 0; t < NT; t += 2) {
    KTILE(t, 0)
    KTILE(t + 1, 1)
  }

  // ---- epilogue: C/D layout col=lane&15, row=(lane>>4)*4+r ----
  const int orow = (lane >> 4) * 4;
  const int ocol = lane & 15;
#pragma unroll
  for (int mi = 0; mi < 8; ++mi)
#pragma unroll
    for (int ni = 0; ni < 4; ++ni) {
      const long r0 = a_row0 + wr * 128 + mi * 16 + orow;
      const long c0 = b_row0 + wc * 64 + ni * 16 + ocol;
#pragma unroll
      for (int r = 0; r < 4; ++r) C[(r0 + r) * N + c0] = acc[mi][ni][r];
    }
}

// ---------------------------------------------------------------------------
// Launch
// ---------------------------------------------------------------------------
extern "C" void kernel_launch(void* const* d_in, const int* in_sizes, int n_in,
                              void* d_out, int out_size, void* d_ws,
                              size_t ws_size, hipStream_t stream) {
  const float* x = (const float*)d_in[0];
  const float* w = (const float*)d_in[1];
  float* out = (float*)d_out;

  const int K = 4096;
  const long M = (long)in_sizes[0] / K;  // 8192
  const int N = in_sizes[1] / K;         // 4096

  ushort_t* xsp = (ushort_t*)d_ws;      // [M][K] bf16
  ushort_t* wb = xsp + (long)M * K;     // [N][K] bf16

  const long n8x = M * K / 8;
  prune_cast_kernel<<<(int)((n8x + 255) / 256), 256, 0, stream>>>(x, xsp, n8x);

  const long n8w = (long)N * K / 8;
  cast_bf16_kernel<<<(int)((n8w + 255) / 256), 256, 0, stream>>>(w, wb, n8w);

  const int nwg = (int)(M / 256) * (N / 256);  // 512, divisible by 8
  gemm256_kernel<<<nwg, 512, 0, stream>>>(xsp, wb, out, (int)M, N, K);
}

// Round 10
// 389.649 us; speedup vs baseline: 1.0978x; 1.0978x over previous
//
#include <hip/hip_runtime.h>
#include <hip/hip_bf16.h>

typedef float f32x4 __attribute__((ext_vector_type(4)));
typedef __bf16 bf16x8 __attribute__((ext_vector_type(8)));
typedef unsigned short ushort_t;
typedef ushort_t u16x8 __attribute__((ext_vector_type(8)));

// ---------------------------------------------------------------------------
// fp32 -> bf16 round-to-nearest-even
// ---------------------------------------------------------------------------
__device__ inline ushort_t f2bf_rne(float f) {
  unsigned u = __builtin_bit_cast(unsigned, f);
  unsigned r = (u + 0x7fffu + ((u >> 16) & 1u)) >> 16;
  return (ushort_t)r;
}

// ---------------------------------------------------------------------------
// Kernel 1: 2:4 prune (exact fp32 argsort-stable semantics) + cast to bf16.
// ---------------------------------------------------------------------------
__global__ void prune_cast_kernel(const float* __restrict__ x,
                                  ushort_t* __restrict__ xsp, long n8) {
  long i = (long)blockIdx.x * blockDim.x + threadIdx.x;
  if (i >= n8) return;
  const float4* p = reinterpret_cast<const float4*>(x);
  float4 g0 = p[2 * i];
  float4 g1 = p[2 * i + 1];
  float v[8] = {g0.x, g0.y, g0.z, g0.w, g1.x, g1.y, g1.z, g1.w};
  u16x8 o;
#pragma unroll
  for (int g = 0; g < 2; ++g) {
    float a[4];
#pragma unroll
    for (int j = 0; j < 4; ++j) a[j] = fabsf(v[g * 4 + j]);
#pragma unroll
    for (int j = 0; j < 4; ++j) {
      int rank = 0;
#pragma unroll
      for (int k = 0; k < 4; ++k) {
        if (k == j) continue;
        rank += (a[k] < a[j]) || (a[k] == a[j] && k < j);
      }
      o[g * 4 + j] = (rank >= 2) ? f2bf_rne(v[g * 4 + j]) : (ushort_t)0;
    }
  }
  reinterpret_cast<u16x8*>(xsp)[i] = o;
}

// ---------------------------------------------------------------------------
// Kernel 2: fp32 -> bf16 cast of the weight matrix.
// ---------------------------------------------------------------------------
__global__ void cast_bf16_kernel(const float* __restrict__ w,
                                 ushort_t* __restrict__ wb, long n8) {
  long i = (long)blockIdx.x * blockDim.x + threadIdx.x;
  if (i >= n8) return;
  const float4* p = reinterpret_cast<const float4*>(w);
  float4 g0 = p[2 * i];
  float4 g1 = p[2 * i + 1];
  u16x8 o;
  o[0] = f2bf_rne(g0.x); o[1] = f2bf_rne(g0.y);
  o[2] = f2bf_rne(g0.z); o[3] = f2bf_rne(g0.w);
  o[4] = f2bf_rne(g1.x); o[5] = f2bf_rne(g1.y);
  o[6] = f2bf_rne(g1.z); o[7] = f2bf_rne(g1.w);
  reinterpret_cast<u16x8*>(wb)[i] = o;
}

// ---------------------------------------------------------------------------
// Kernel 3: 128x128 bf16 GEMM, 2 blocks/CU, ONE barrier per K-tile.
// C[m][n] = sum_k A[m][k]*B[n][k].  4 waves (2Mx2N), BK=64, 64 KiB LDS per
// block (A 2x16KiB + B 2x16KiB double-buffered) -> TWO resident blocks per
// CU: independent barrier domains hide each other's sync/latency stalls
// (m114: cross-wave MFMA co-issue).  3-bit XOR swizzle (physical chunk =
// logical ^ (row&7)) -> 0 bank conflicts (row stride still 128 B, math
// identical to the 256-tile version).
//
// Per tile t (parity PAR):
//   - stage A(t+1) -> PAR^1 at tile start (max flight)
//   - A/B fragment ds_reads (PAR) + first 16 MFMAs
//   - stage B(t+1) -> PAR^1 mid-tile
//   - last 16 MFMAs
//   - vmcnt(0) (stages issued 1100-2200 cyc earlier; L2-resident) + barrier
// Stage-write safety: PAR^1 reads were consumed before tile (t-1)'s end
// barrier, which all waves passed before issuing these stages.
// Branch-free tail: stage index clamps to NT-1 (junk lands in dead slots).
// ---------------------------------------------------------------------------
#define BARM()                              \
  asm volatile("" ::: "memory");            \
  __builtin_amdgcn_s_barrier();             \
  asm volatile("" ::: "memory");
#define WAIT_VM0() asm volatile("s_waitcnt vmcnt(0)" ::: "memory")

// 4 instrs: wave w covers rows w*32 + i*8 + (l>>3), i = 0..3
#define STAGE_A(t1, par)                                                       \
  _Pragma("unroll") for (int i_ = 0; i_ < 4; ++i_) {                           \
    const ushort_t* g =                                                        \
        A + (a_row0 + w * 32 + i_ * 8 + srow8) * (long)Kd + (t1) * 64 + scol;  \
    __builtin_amdgcn_global_load_lds(                                          \
        (const __attribute__((address_space(1))) void*)g,                      \
        (__attribute__((address_space(3))) void*)&ldsA[(par) * 8192 +          \
                                                       (w * 32 + i_ * 8) * 64 +\
                                                       lane * 8],              \
        16, 0, 0);                                                             \
  }

#define STAGE_B(t1, par)                                                       \
  _Pragma("unroll") for (int i_ = 0; i_ < 4; ++i_) {                           \
    const ushort_t* g =                                                        \
        B + (b_row0 + w * 32 + i_ * 8 + srow8) * (long)Kd + (t1) * 64 + scol;  \
    __builtin_amdgcn_global_load_lds(                                          \
        (const __attribute__((address_space(1))) void*)g,                      \
        (__attribute__((address_space(3))) void*)&ldsB[(par) * 8192 +          \
                                                       (w * 32 + i_ * 8) * 64 +\
                                                       lane * 8],              \
        16, 0, 0);                                                             \
  }

#define LDA_FRAG(dst, par, mi, s)                                              \
  dst = *reinterpret_cast<const bf16x8*>(                                      \
      reinterpret_cast<const char*>(ldsA) + (par) * 16384 +                    \
      (wr * 64 + (mi) * 16) * 128 + ((s) ? roff1 : roff0));

#define LDB_FRAG(dst, par, ni, s)                                              \
  dst = *reinterpret_cast<const bf16x8*>(                                      \
      reinterpret_cast<const char*>(ldsB) + (par) * 16384 +                    \
      (wc * 64 + (ni) * 16) * 128 + ((s) ? roff1 : roff0));

// s-outer halves: 16 MFMAs each, dep distance 8 on acc registers.
#define MFMA_H(NLO)                                                            \
  __builtin_amdgcn_s_setprio(1);                                               \
  _Pragma("unroll") for (int s = 0; s < 2; ++s)                                \
  _Pragma("unroll") for (int mi = 0; mi < 4; ++mi)                             \
  _Pragma("unroll") for (int ni = (NLO); ni < (NLO) + 2; ++ni)                 \
      acc[mi][ni] = __builtin_amdgcn_mfma_f32_16x16x32_bf16(                   \
          af[mi][s], bfr[ni][s], acc[mi][ni], 0, 0, 0);                        \
  __builtin_amdgcn_s_setprio(0);

#define KTILE(t, PAR)                                                          \
  {                                                                            \
    const int tN = ((t) + 1 < NT) ? (t) + 1 : NT - 1;                          \
    STAGE_A(tN, (PAR) ^ 1)                                                     \
    _Pragma("unroll") for (int mi = 0; mi < 4; ++mi)                           \
    _Pragma("unroll") for (int s = 0; s < 2; ++s)                              \
        LDA_FRAG(af[mi][s], PAR, mi, s)                                        \
    _Pragma("unroll") for (int ni = 0; ni < 4; ++ni)                           \
    _Pragma("unroll") for (int s = 0; s < 2; ++s)                              \
        LDB_FRAG(bfr[ni][s], PAR, ni, s)                                       \
    MFMA_H(0)                                                                  \
    STAGE_B(tN, (PAR) ^ 1)                                                     \
    MFMA_H(2)                                                                  \
    WAIT_VM0();                                                                \
    BARM()                                                                     \
  }

__global__ __launch_bounds__(256, 2) void gemm128_kernel(
    const ushort_t* __restrict__ A,  // [M][K] bf16 (pruned x)
    const ushort_t* __restrict__ B,  // [N][K] bf16 (weight)
    float* __restrict__ C,           // [M][N] fp32
    int M, int N, int Kd) {
  __shared__ ushort_t ldsA[2 * 8192];  // 2 parity x 16 KiB
  __shared__ ushort_t ldsB[2 * 8192];

  const int tid = threadIdx.x;
  const int lane = tid & 63;
  const int w = tid >> 6;   // wave 0..3
  const int wr = w >> 1;    // 0..1 -> 64-row half
  const int wc = w & 1;     // 0..1 -> 64-col half

  // XCD-bijective grid swizzle (gridDim.x % 8 == 0)
  const int b = blockIdx.x;
  const int wg = (b & 7) * (gridDim.x >> 3) + (b >> 3);
  const int nbn = N / 128;
  const int bm = wg / nbn, bn = wg % nbn;
  const long a_row0 = (long)bm * 128;
  const long b_row0 = (long)bn * 128;
  const int NT = Kd / 64;

  // staging: lane l writes LINEAR physical (row +(l>>3), chunk l&7);
  // swizzle physical(r,c) <- logical(r, c^(r&7)) -> SOURCE chunk =
  // (l&7) ^ ((l>>3)&7)  (rows differ by multiples of 8 across instrs).
  const int srow8 = lane >> 3;
  const int scol = (((lane & 7) ^ ((lane >> 3) & 7)) << 3);  // ushort units

  // fragment read: logical (row rl, chunk q|s<<2) -> physical chunk
  // (q|s<<2) ^ (rl&7); s folded inside the XOR -> two precomputed offsets.
  const int rl = lane & 15;
  const int q = lane >> 4;
  const int roff0 = rl * 128 + (((q) ^ (rl & 7)) << 4);
  const int roff1 = rl * 128 + (((q | 4) ^ (rl & 7)) << 4);

  f32x4 acc[4][4];
#pragma unroll
  for (int i = 0; i < 4; ++i)
#pragma unroll
    for (int j = 0; j < 4; ++j) acc[i][j] = f32x4{0.f, 0.f, 0.f, 0.f};

  bf16x8 af[4][2];   // A fragments for this wave's 64 rows
  bf16x8 bfr[4][2];  // B fragments for this wave's 64 cols

  // ---- prologue: stage tile 0 into parity 0, drain, sync ----
  STAGE_A(0, 0)
  STAGE_B(0, 0)
  WAIT_VM0();
  BARM()

  for (int t = 0; t < NT; t += 2) {
    KTILE(t, 0)
    KTILE(t + 1, 1)
  }

  // ---- epilogue: C/D layout col=lane&15, row=(lane>>4)*4+r ----
  const int orow = (lane >> 4) * 4;
  const int ocol = lane & 15;
#pragma unroll
  for (int mi = 0; mi < 4; ++mi)
#pragma unroll
    for (int ni = 0; ni < 4; ++ni) {
      const long r0 = a_row0 + wr * 64 + mi * 16 + orow;
      const long c0 = b_row0 + wc * 64 + ni * 16 + ocol;
#pragma unroll
      for (int r = 0; r < 4; ++r) C[(r0 + r) * N + c0] = acc[mi][ni][r];
    }
}

// ---------------------------------------------------------------------------
// Launch
// ---------------------------------------------------------------------------
extern "C" void kernel_launch(void* const* d_in, const int* in_sizes, int n_in,
                              void* d_out, int out_size, void* d_ws,
                              size_t ws_size, hipStream_t stream) {
  const float* x = (const float*)d_in[0];
  const float* w = (const float*)d_in[1];
  float* out = (float*)d_out;

  const int K = 4096;
  const long M = (long)in_sizes[0] / K;  // 8192
  const int N = in_sizes[1] / K;         // 4096

  ushort_t* xsp = (ushort_t*)d_ws;      // [M][K] bf16
  ushort_t* wb = xsp + (long)M * K;     // [N][K] bf16

  const long n8x = M * K / 8;
  prune_cast_kernel<<<(int)((n8x + 255) / 256), 256, 0, stream>>>(x, xsp, n8x);

  const long n8w = (long)N * K / 8;
  cast_bf16_kernel<<<(int)((n8w + 255) / 256), 256, 0, stream>>>(w, wb, n8w);

  const int nwg = (int)(M / 128) * (N / 128);  // 2048, divisible by 8
  gemm128_kernel<<<nwg, 256, 0, stream>>>(xsp, wb, out, (int)M, N, K);
}

// Round 11
// 306.216 us; speedup vs baseline: 1.3969x; 1.2725x over previous
//
#include <hip/hip_runtime.h>
#include <hip/hip_bf16.h>

typedef float f32x4 __attribute__((ext_vector_type(4)));
typedef float f32x16 __attribute__((ext_vector_type(16)));
typedef __bf16 bf16x8 __attribute__((ext_vector_type(8)));
typedef unsigned short ushort_t;
typedef ushort_t u16x8 __attribute__((ext_vector_type(8)));

// ---------------------------------------------------------------------------
// fp32 -> bf16 round-to-nearest-even
// ---------------------------------------------------------------------------
__device__ inline ushort_t f2bf_rne(float f) {
  unsigned u = __builtin_bit_cast(unsigned, f);
  unsigned r = (u + 0x7fffu + ((u >> 16) & 1u)) >> 16;
  return (ushort_t)r;
}

// ---------------------------------------------------------------------------
// Kernel 1: 2:4 prune (exact fp32 argsort-stable semantics) + cast to bf16.
// ---------------------------------------------------------------------------
__global__ void prune_cast_kernel(const float* __restrict__ x,
                                  ushort_t* __restrict__ xsp, long n8) {
  long i = (long)blockIdx.x * blockDim.x + threadIdx.x;
  if (i >= n8) return;
  const float4* p = reinterpret_cast<const float4*>(x);
  float4 g0 = p[2 * i];
  float4 g1 = p[2 * i + 1];
  float v[8] = {g0.x, g0.y, g0.z, g0.w, g1.x, g1.y, g1.z, g1.w};
  u16x8 o;
#pragma unroll
  for (int g = 0; g < 2; ++g) {
    float a[4];
#pragma unroll
    for (int j = 0; j < 4; ++j) a[j] = fabsf(v[g * 4 + j]);
#pragma unroll
    for (int j = 0; j < 4; ++j) {
      int rank = 0;
#pragma unroll
      for (int k = 0; k < 4; ++k) {
        if (k == j) continue;
        rank += (a[k] < a[j]) || (a[k] == a[j] && k < j);
      }
      o[g * 4 + j] = (rank >= 2) ? f2bf_rne(v[g * 4 + j]) : (ushort_t)0;
    }
  }
  reinterpret_cast<u16x8*>(xsp)[i] = o;
}

// ---------------------------------------------------------------------------
// Kernel 2: fp32 -> bf16 cast of the weight matrix.
// ---------------------------------------------------------------------------
__global__ void cast_bf16_kernel(const float* __restrict__ w,
                                 ushort_t* __restrict__ wb, long n8) {
  long i = (long)blockIdx.x * blockDim.x + threadIdx.x;
  if (i >= n8) return;
  const float4* p = reinterpret_cast<const float4*>(w);
  float4 g0 = p[2 * i];
  float4 g1 = p[2 * i + 1];
  u16x8 o;
  o[0] = f2bf_rne(g0.x); o[1] = f2bf_rne(g0.y);
  o[2] = f2bf_rne(g0.z); o[3] = f2bf_rne(g0.w);
  o[4] = f2bf_rne(g1.x); o[5] = f2bf_rne(g1.y);
  o[6] = f2bf_rne(g1.z); o[7] = f2bf_rne(g1.w);
  reinterpret_cast<u16x8*>(wb)[i] = o;
}

// ---------------------------------------------------------------------------
// Kernel 3: 256x256 bf16 GEMM, round-7 schedule, MFMA 32x32x16 shape.
// C[m][n] = sum_k A[m][k]*B[n][k].  8 waves (2Mx4N), BK=64, 128 KiB LDS
// double-buffered, 3-bit XOR swizzle (physical 16B-chunk = logical ^ (row&7))
// -> 0 bank conflicts.
//
// Shape change (this round's single variable): 16x16x32 -> 32x32x16.
// 32x32 µbench ceiling 2495 TF vs 16x16's 2075-2176 (+13-15%), half the
// MFMA instruction count.  Per wave: 4 m-subtiles x 2 n-subtiles of 32x32,
// acc = f32x16[4][2] (128 VGPR, same as before).
// A-frag lane l: row = l&31, k = (l>>5)*8 + j (contiguous 8, symmetric to
// the verified 16x16x32 layout).  C/D: col = lane&31,
// row = (reg&3) + 8*(reg>>2) + 4*(lane>>5)  [m74/m101].
//
// Schedule = round 7 verbatim: A(t+1)->PAR^1 staged early in region 1;
// mid-BAR after all B-consuming MFMA; B(t+2)->PAR staged after mid-BAR;
// tile-end counted vmcnt(4) (keeps B(t+2) in flight), tail vmcnt(0).
// ---------------------------------------------------------------------------
#define BARM()                              \
  asm volatile("" ::: "memory");            \
  __builtin_amdgcn_s_barrier();             \
  asm volatile("" ::: "memory");
#define WAIT_VM4() asm volatile("s_waitcnt vmcnt(4)" ::: "memory")
#define WAIT_VM0() asm volatile("s_waitcnt vmcnt(0)" ::: "memory")

#define STAGE_A(t1, h, par)                                                    \
  {                                                                            \
    const ushort_t* g0 =                                                       \
        A + (a_row0 + (h) * 128 + srow) * (long)Kd + (t1) * 64 + scol;         \
    const ushort_t* g1 =                                                       \
        A + (a_row0 + (h) * 128 + srow + 8) * (long)Kd + (t1) * 64 + scol;     \
    ushort_t* l0 = &ldsA[((par) * 2 + (h)) * 8192 + w * 1024];                 \
    __builtin_amdgcn_global_load_lds(                                          \
        (const __attribute__((address_space(1))) void*)g0,                     \
        (__attribute__((address_space(3))) void*)l0, 16, 0, 0);                \
    __builtin_amdgcn_global_load_lds(                                          \
        (const __attribute__((address_space(1))) void*)g1,                     \
        (__attribute__((address_space(3))) void*)(l0 + 512), 16, 0, 0);        \
  }

#define STAGE_B(t1, h, par)                                                    \
  {                                                                            \
    const ushort_t* g0 =                                                       \
        B + (b_row0 + (h) * 128 + srow) * (long)Kd + (t1) * 64 + scol;         \
    const ushort_t* g1 =                                                       \
        B + (b_row0 + (h) * 128 + srow + 8) * (long)Kd + (t1) * 64 + scol;     \
    ushort_t* l0 = &ldsB[((par) * 2 + (h)) * 8192 + w * 1024];                 \
    __builtin_amdgcn_global_load_lds(                                          \
        (const __attribute__((address_space(1))) void*)g0,                     \
        (__attribute__((address_space(3))) void*)l0, 16, 0, 0);                \
    __builtin_amdgcn_global_load_lds(                                          \
        (const __attribute__((address_space(1))) void*)g1,                     \
        (__attribute__((address_space(3))) void*)(l0 + 512), 16, 0, 0);        \
  }

// A subtile mi (0..3): rows wr*128 + mi*32 + (l&31); k-chunk (ks*2+q32)^swz
#define LDA_FRAG(dst, par, mi, ks)                                             \
  dst = *reinterpret_cast<const bf16x8*>(                                      \
      reinterpret_cast<const char*>(ldsA) + ((par) * 2 + wr) * 16384 +         \
      (mi) * 4096 + rowb + koff[ks]);

// B subtile ni (0..1): rows wc*64 + ni*32 + (l&31)
#define LDB_FRAG(dst, par, ni, ks)                                             \
  dst = *reinterpret_cast<const bf16x8*>(                                      \
      reinterpret_cast<const char*>(ldsB) + ((par) * 2 + (wc >> 1)) * 16384 +  \
      (wc & 1) * 8192 + (ni) * 4096 + rowb + koff[ks]);

// m-half 0, both n: 16 MFMA, acc dep distance 4 (ks-outer)
#define MFMA_H0()                                                              \
  __builtin_amdgcn_s_setprio(1);                                               \
  _Pragma("unroll") for (int ks = 0; ks < 4; ++ks)                             \
  _Pragma("unroll") for (int mi2 = 0; mi2 < 2; ++mi2)                          \
  _Pragma("unroll") for (int ni = 0; ni < 2; ++ni)                             \
      acc[mi2][ni] = __builtin_amdgcn_mfma_f32_32x32x16_bf16(                  \
          af[mi2][ks], bfr[ni][ks], acc[mi2][ni], 0, 0, 0);                    \
  __builtin_amdgcn_s_setprio(0);

// m-half 1, one n-column: 8 MFMA, dep distance 2
#define MFMA_Q1(NH)                                                            \
  __builtin_amdgcn_s_setprio(1);                                               \
  _Pragma("unroll") for (int ks = 0; ks < 4; ++ks)                             \
  _Pragma("unroll") for (int mi2 = 0; mi2 < 2; ++mi2)                          \
      acc[2 + mi2][NH] = __builtin_amdgcn_mfma_f32_32x32x16_bf16(              \
          af[mi2][ks], bfr[NH][ks], acc[2 + mi2][NH], 0, 0, 0);                \
  __builtin_amdgcn_s_setprio(0);

#define KTILE(t, PAR)                                                          \
  {                                                                            \
    const int tA = ((t) + 1 < NT) ? (t) + 1 : NT - 1;                          \
    const int tB = ((t) + 2 < NT) ? (t) + 2 : NT - 1;                          \
    /* region 1: A mh0 + all B reads ; stage A(t+1,op) ; 24 MFMA */            \
    _Pragma("unroll") for (int mi2 = 0; mi2 < 2; ++mi2)                        \
    _Pragma("unroll") for (int ks = 0; ks < 4; ++ks)                           \
        LDA_FRAG(af[mi2][ks], PAR, mi2, ks)                                    \
    _Pragma("unroll") for (int ni = 0; ni < 2; ++ni)                           \
    _Pragma("unroll") for (int ks = 0; ks < 4; ++ks)                           \
        LDB_FRAG(bfr[ni][ks], PAR, ni, ks)                                     \
    STAGE_A(tA, 0, (PAR) ^ 1)                                                  \
    STAGE_A(tA, 1, (PAR) ^ 1)                                                  \
    MFMA_H0()                                                                  \
    _Pragma("unroll") for (int mi2 = 0; mi2 < 2; ++mi2)                        \
    _Pragma("unroll") for (int ks = 0; ks < 4; ++ks)                           \
        LDA_FRAG(af[mi2][ks], PAR, 2 + mi2, ks)                                \
    MFMA_Q1(1)                                                                 \
    /* all B reads consumed on every wave -> B slots may be restaged */        \
    BARM()                                                                     \
    STAGE_B(tB, 0, PAR)                                                        \
    STAGE_B(tB, 1, PAR)                                                        \
    MFMA_Q1(0)                                                                 \
    if ((t) + 2 < NT) { WAIT_VM4(); } else { WAIT_VM0(); }                     \
    BARM()                                                                     \
  }

__global__ __launch_bounds__(512, 1) void gemm256_kernel(
    const ushort_t* __restrict__ A,  // [M][K] bf16 (pruned x)
    const ushort_t* __restrict__ B,  // [N][K] bf16 (weight)
    float* __restrict__ C,           // [M][N] fp32
    int M, int N, int Kd) {
  __shared__ ushort_t ldsA[4 * 8192];  // 4 slots x 16 KiB (par,half)
  __shared__ ushort_t ldsB[4 * 8192];

  const int tid = threadIdx.x;
  const int lane = tid & 63;
  const int w = tid >> 6;   // wave 0..7
  const int wr = w >> 2;    // 0..1 -> 128-row half
  const int wc = w & 3;     // 0..3 -> 64-col slab

  // XCD-bijective grid swizzle (gridDim.x % 8 == 0)
  const int b = blockIdx.x;
  const int wg = (b & 7) * (gridDim.x >> 3) + (b >> 3);
  const int nbn = N / 256;
  const int bm = wg / nbn, bn = wg % nbn;
  const long a_row0 = (long)bm * 256;
  const long b_row0 = (long)bn * 256;
  const int NT = Kd / 64;

  // staging: instr i of wave w, lane l writes LINEAR physical (row
  // 16w+8i+(l>>3), chunk l&7); swizzle physical(r,c) <- logical(r, c^(r&7))
  // -> global SOURCE chunk = (l&7) ^ ((l>>3)&7)  (same for both instrs).
  const int srow = w * 16 + (lane >> 3);
  const int scol = (((lane & 7) ^ ((lane >> 3) & 7)) << 3);  // ushort units

  // 32x32 fragment read: lane l -> row (l&31), logical chunk ks*2 + (l>>5);
  // physical chunk = logical ^ (row&7).
  const int rl32 = lane & 31;
  const int q32 = lane >> 5;
  const int rowb = rl32 * 128;  // bytes
  const int rx = rl32 & 7;
  int koff[4];
#pragma unroll
  for (int ks = 0; ks < 4; ++ks) koff[ks] = ((ks * 2 + q32) ^ rx) << 4;

  f32x16 acc[4][2];  // [m-subtile][n-subtile], 128 VGPR
#pragma unroll
  for (int i = 0; i < 4; ++i)
#pragma unroll
    for (int j = 0; j < 2; ++j)
#pragma unroll
      for (int r = 0; r < 16; ++r) acc[i][j][r] = 0.f;

  bf16x8 af[2][4];   // current m-half A fragments [mi2][ks]
  bf16x8 bfr[2][4];  // both n-subtile B fragments [ni][ks]

  // ---- prologue: stage tile 0 (par0) fully + B of tile 1 (par1) ----
  STAGE_A(0, 0, 0)
  STAGE_A(0, 1, 0)
  STAGE_B(0, 0, 0)
  STAGE_B(0, 1, 0)
  STAGE_B(1, 0, 1)
  STAGE_B(1, 1, 1)
  WAIT_VM4();
  BARM()

  for (int t = 0; t < NT; t += 2) {
    KTILE(t, 0)
    KTILE(t + 1, 1)
  }

  // ---- epilogue: 32x32 C/D layout col=lane&31, row=(r&3)+8*(r>>2)+4*q32 ----
#pragma unroll
  for (int mi = 0; mi < 4; ++mi)
#pragma unroll
    for (int ni = 0; ni < 2; ++ni) {
      const long c0 = b_row0 + wc * 64 + ni * 32 + rl32;
      const long r0 = a_row0 + wr * 128 + mi * 32 + q32 * 4;
#pragma unroll
      for (int r = 0; r < 16; ++r) {
        const long row = r0 + (r & 3) + 8 * (r >> 2);
        C[row * N + c0] = acc[mi][ni][r];
      }
    }
}

// ---------------------------------------------------------------------------
// Launch
// ---------------------------------------------------------------------------
extern "C" void kernel_launch(void* const* d_in, const int* in_sizes, int n_in,
                              void* d_out, int out_size, void* d_ws,
                              size_t ws_size, hipStream_t stream) {
  const float* x = (const float*)d_in[0];
  const float* w = (const float*)d_in[1];
  float* out = (float*)d_out;

  const int K = 4096;
  const long M = (long)in_sizes[0] / K;  // 8192
  const int N = in_sizes[1] / K;         // 4096

  ushort_t* xsp = (ushort_t*)d_ws;      // [M][K] bf16
  ushort_t* wb = xsp + (long)M * K;     // [N][K] bf16

  const long n8x = M * K / 8;
  prune_cast_kernel<<<(int)((n8x + 255) / 256), 256, 0, stream>>>(x, xsp, n8x);

  const long n8w = (long)N * K / 8;
  cast_bf16_kernel<<<(int)((n8w + 255) / 256), 256, 0, stream>>>(w, wb, n8w);

  const int nwg = (int)(M / 256) * (N / 256);  // 512, divisible by 8
  gemm256_kernel<<<nwg, 512, 0, stream>>>(xsp, wb, out, (int)M, N, K);
}